// Round 1
// baseline (613.703 us; speedup 1.0000x reference)
//
#include <hip/hip_runtime.h>
#include <hip/hip_bf16.h>
#include <cstdint>

typedef __attribute__((ext_vector_type(8))) short s16x8;   // 8 bf16 = 4 VGPRs
typedef __attribute__((ext_vector_type(4))) float f32x4;   // MFMA C/D

union CV2 { __hip_bfloat162 h; uint32_t u; };

// ---------------------------------------------------------------------------
// Prep kernel (unchanged): fold ln_w into W, ln_b + b into b', column sums S,
// and swizzle W' into MFMA B-fragment order as bf16.
//   Wb flat bf16 idx for (o,k): kk=k>>5, q=(k&31)>>3, j=k&7, t=o>>4, n=o&15,
//   lane l=q*16+n  ->  ((kk*4+t)*64 + l)*8 + j
// ---------------------------------------------------------------------------
__global__ void prep_kernel(const float* __restrict__ W,
                            const float* __restrict__ lnw,
                            const float* __restrict__ lnb,
                            const float* __restrict__ bias,
                            __hip_bfloat16* __restrict__ Wb,
                            float* __restrict__ Ssum,
                            float* __restrict__ bp) {
    const int o = blockIdx.x;      // 0..63
    const int tid = threadIdx.x;   // 0..255
    float s = 0.f, bb = 0.f;
    for (int k = tid; k < 768; k += 256) {
        float wraw = W[o * 768 + k];
        float wv = lnw[k] * wraw;
        s += wv;
        bb += lnb[k] * wraw;
        int kk = k >> 5, rem = k & 31;
        int q = rem >> 3, j = rem & 7;
        int t = o >> 4, n = o & 15;
        int l = q * 16 + n;
        Wb[(kk * 4 + t) * 512 + l * 8 + j] = __float2bfloat16(wv);
    }
    __shared__ float rs[4], rb[4];
    for (int off = 32; off > 0; off >>= 1) {
        s  += __shfl_down(s, off);
        bb += __shfl_down(bb, off);
    }
    int wid = tid >> 6;
    if ((tid & 63) == 0) { rs[wid] = s; rb[wid] = bb; }
    __syncthreads();
    if (tid == 0) {
        Ssum[o] = rs[0] + rs[1] + rs[2] + rs[3];
        bp[o]   = bias[o] + rb[0] + rb[1] + rb[2] + rb[3];
    }
}

// ---------------------------------------------------------------------------
// R5: barrier-free, LDS-free main loop.
// KEY INSIGHT: the 16x16x32 A-fragment for lane l is 8 CONTIGUOUS k-elements
// of one x-row = 32 contiguous fp32 bytes in GLOBAL memory. So each lane
// loads its own two float4 per (chunk, subtile) directly from HBM, computes
// LN stats on fp32 in-register, packs to bf16, and feeds MFMA. No x LDS
// round-trip, no barriers, no staging convoy. Wb (96 KB, shared by all 2048
// blocks) is L1/L2-hot and read per-fragment, perfectly coalesced
// (lane l reads Wb4[frag*64 + l] -> 1 KB/wave/instr).
// Chunk-deep x prefetch (8 float4/lane = 8 KB/wave in flight); with 3
// blocks/CU (12 waves) that is ~96 KB in flight per CU >> the ~22 KB
// Little's-law requirement at 6.3 TB/s.
// LDS: 16 KB epilogue buffer only -> occupancy capped by VGPRs (bounds 256,3).
// ---------------------------------------------------------------------------
__global__ __launch_bounds__(256, 3) void fused_kernel(
        const float* __restrict__ x,
        const uint4* __restrict__ Wb4,
        const float* __restrict__ Ssum,
        const float* __restrict__ bp,
        float* __restrict__ out) {
    const int b   = blockIdx.x;
    const int tid = threadIdx.x;
    const int w   = tid >> 6;   // wave 0..3 -> rows w*16..w*16+15
    const int l   = tid & 63;
    const int q   = l >> 4;     // quad 0..3 -> k-offset q*8 within 32-chunk
    const int n   = l & 15;     // A-row within wave's 16-row group

    __shared__ __align__(16) float sout[4096];   // epilogue only (16 KB)

    // lane's private x stream: row (w*16+n), k base q*8
    const float* xr = x + (size_t)b * 49152 + (w * 16 + n) * 768 + q * 8;
    const uint4* Wl = Wb4 + l;

    f32x4 acc0 = {0.f, 0.f, 0.f, 0.f};
    f32x4 acc1 = acc0, acc2 = acc0, acc3 = acc0;
    float sum = 0.f, ssq = 0.f;

    float4 cur[8], nxt[8];
    // ---- prefetch chunk 0 ----
    #pragma unroll
    for (int s = 0; s < 4; s++) {
        cur[2 * s]     = *(const float4*)(xr + s * 32);
        cur[2 * s + 1] = *(const float4*)(xr + s * 32 + 4);
    }

    #pragma unroll
    for (int c = 0; c < 6; c++) {
        // ---- stats (fp32) + pack A-fragments to bf16, freeing cur ----
        s16x8 af[4];
        #pragma unroll
        for (int s = 0; s < 4; s++) {
            float4 lo = cur[2 * s], hi = cur[2 * s + 1];
            sum += lo.x; ssq = fmaf(lo.x, lo.x, ssq);
            sum += lo.y; ssq = fmaf(lo.y, lo.y, ssq);
            sum += lo.z; ssq = fmaf(lo.z, lo.z, ssq);
            sum += lo.w; ssq = fmaf(lo.w, lo.w, ssq);
            sum += hi.x; ssq = fmaf(hi.x, hi.x, ssq);
            sum += hi.y; ssq = fmaf(hi.y, hi.y, ssq);
            sum += hi.z; ssq = fmaf(hi.z, hi.z, ssq);
            sum += hi.w; ssq = fmaf(hi.w, hi.w, ssq);
            CV2 p0, p1, p2, p3;
            p0.h = __float22bfloat162_rn(make_float2(lo.x, lo.y));
            p1.h = __float22bfloat162_rn(make_float2(lo.z, lo.w));
            p2.h = __float22bfloat162_rn(make_float2(hi.x, hi.y));
            p3.h = __float22bfloat162_rn(make_float2(hi.z, hi.w));
            af[s] = __builtin_bit_cast(s16x8,
                        make_uint4(p0.u, p1.u, p2.u, p3.u));
        }

        // ---- issue next-chunk x loads (HBM), one full chunk of cover ----
        if (c < 5) {
            #pragma unroll
            for (int s = 0; s < 4; s++) {
                nxt[2 * s]     = *(const float4*)(xr + (c + 1) * 128 + s * 32);
                nxt[2 * s + 1] = *(const float4*)(xr + (c + 1) * 128 + s * 32 + 4);
            }
        }

        // ---- MFMA with per-subtile Wb fragments straight from L1/L2 ----
        #pragma unroll
        for (int s = 0; s < 4; s++) {
            uint4 wb0 = Wl[((c * 4 + s) * 4 + 0) * 64];
            uint4 wb1 = Wl[((c * 4 + s) * 4 + 1) * 64];
            uint4 wb2 = Wl[((c * 4 + s) * 4 + 2) * 64];
            uint4 wb3 = Wl[((c * 4 + s) * 4 + 3) * 64];
            acc0 = __builtin_amdgcn_mfma_f32_16x16x32_bf16(
                       af[s], __builtin_bit_cast(s16x8, wb0), acc0, 0, 0, 0);
            acc1 = __builtin_amdgcn_mfma_f32_16x16x32_bf16(
                       af[s], __builtin_bit_cast(s16x8, wb1), acc1, 0, 0, 0);
            acc2 = __builtin_amdgcn_mfma_f32_16x16x32_bf16(
                       af[s], __builtin_bit_cast(s16x8, wb2), acc2, 0, 0, 0);
            acc3 = __builtin_amdgcn_mfma_f32_16x16x32_bf16(
                       af[s], __builtin_bit_cast(s16x8, wb3), acc3, 0, 0, 0);
        }

        if (c < 5) {
            #pragma unroll
            for (int i = 0; i < 8; i++) cur[i] = nxt[i];
        }
    }

    // ---- row stats: reduce across the 4 lanes sharing row n (xor 16, 32) ----
    sum += __shfl_xor(sum, 16); sum += __shfl_xor(sum, 32);
    ssq += __shfl_xor(ssq, 16); ssq += __shfl_xor(ssq, 32);
    const float mu   = sum * (1.0f / 768.0f);
    const float rstd = rsqrtf(ssq * (1.0f / 768.0f) - mu * mu + 1e-5f);

    float St[4], Bt[4];
    #pragma unroll
    for (int t = 0; t < 4; t++) {
        St[t] = Ssum[t * 16 + n];   // o = 16t + n
        Bt[t] = bp[t * 16 + n];
    }

    // ---- epilogue: SiLU + unpatchify via LDS stage, coalesced stores ----
    const int o2 = (n >> 2) & 3;
    const int o3 = n & 3;
    f32x4 va[4] = {acc0, acc1, acc2, acc3};
    #pragma unroll
    for (int r = 0; r < 4; r++) {
        // D layout: lane holds row m = q*4+r, col n; stats live on lane m.
        float mu_r   = __shfl(mu,   q * 4 + r);
        float rstd_r = __shfl(rstd, q * 4 + r);
        int cc  = w * 16 + q * 4 + r;
        int c1i = cc >> 3, c2i = cc & 7;
        int base = (c1i * 4 + o2) * 32 + c2i * 4 + o3;
        #pragma unroll
        for (int t = 0; t < 4; t++) {
            float y = rstd_r * (va[t][r] - mu_r * St[t]) + Bt[t];
            y = y / (1.0f + __expf(-y));             // SiLU
            sout[t * 1024 + base] = y;               // [c][c1*4+o2][c2*4+o3]
        }
    }
    __syncthreads();

    float* outp = out + (size_t)b * 4096;
    #pragma unroll
    for (int j = 0; j < 4; j++) {
        *(float4*)(outp + j * 1024 + tid * 4) =
            *(const float4*)(&sout[j * 1024 + tid * 4]);
    }
}

extern "C" void kernel_launch(void* const* d_in, const int* in_sizes, int n_in,
                              void* d_out, int out_size, void* d_ws, size_t ws_size,
                              hipStream_t stream) {
    const float* x    = (const float*)d_in[0];
    const float* lnw  = (const float*)d_in[1];
    const float* lnb  = (const float*)d_in[2];
    const float* W    = (const float*)d_in[3];
    const float* bias = (const float*)d_in[4];
    float* out = (float*)d_out;

    const int B = in_sizes[0] / (64 * 768);   // 2048

    __hip_bfloat16* Wb = (__hip_bfloat16*)d_ws;                 // 98304 B
    float* Ssum = (float*)((char*)d_ws + 98304);                // 256 B
    float* bp   = (float*)((char*)d_ws + 98304 + 256);          // 256 B

    prep_kernel<<<64, 256, 0, stream>>>(W, lnw, lnb, bias, Wb, Ssum, bp);
    fused_kernel<<<B, 256, 0, stream>>>(x, (const uint4*)d_ws, Ssum, bp, out);
}

// Round 2
// 539.753 us; speedup vs baseline: 1.1370x; 1.1370x over previous
//
#include <hip/hip_runtime.h>
#include <hip/hip_bf16.h>
#include <cstdint>

typedef __attribute__((ext_vector_type(8))) short s16x8;   // 8 bf16 = 4 VGPRs
typedef __attribute__((ext_vector_type(4))) float f32x4;   // MFMA C/D

union CV2 { __hip_bfloat162 h; uint32_t u; };

// ---------------------------------------------------------------------------
// Prep kernel (unchanged): fold ln_w into W, ln_b + b into b', column sums S,
// and swizzle W' into MFMA B-fragment order as bf16.
//   Wb flat bf16 idx for (o,k): kk=k>>5, q=(k&31)>>3, j=k&7, t=o>>4, n=o&15,
//   lane l=q*16+n  ->  ((kk*4+t)*64 + l)*8 + j
// ---------------------------------------------------------------------------
__global__ void prep_kernel(const float* __restrict__ W,
                            const float* __restrict__ lnw,
                            const float* __restrict__ lnb,
                            const float* __restrict__ bias,
                            __hip_bfloat16* __restrict__ Wb,
                            float* __restrict__ Ssum,
                            float* __restrict__ bp) {
    const int o = blockIdx.x;      // 0..63
    const int tid = threadIdx.x;   // 0..255
    float s = 0.f, bb = 0.f;
    for (int k = tid; k < 768; k += 256) {
        float wraw = W[o * 768 + k];
        float wv = lnw[k] * wraw;
        s += wv;
        bb += lnb[k] * wraw;
        int kk = k >> 5, rem = k & 31;
        int q = rem >> 3, j = rem & 7;
        int t = o >> 4, n = o & 15;
        int l = q * 16 + n;
        Wb[(kk * 4 + t) * 512 + l * 8 + j] = __float2bfloat16(wv);
    }
    __shared__ float rs[4], rb[4];
    for (int off = 32; off > 0; off >>= 1) {
        s  += __shfl_down(s, off);
        bb += __shfl_down(bb, off);
    }
    int wid = tid >> 6;
    if ((tid & 63) == 0) { rs[wid] = s; rb[wid] = bb; }
    __syncthreads();
    if (tid == 0) {
        Ssum[o] = rs[0] + rs[1] + rs[2] + rs[3];
        bp[o]   = bias[o] + rb[0] + rb[1] + rb[2] + rb[3];
    }
}

// ---------------------------------------------------------------------------
// R6: persistent blocks; Wb in LDS (staged ONCE per CU); x direct-to-register.
// LESSON (R5 post-mortem): gfx950 vm loads complete IN ORDER on one queue --
// any global Wb load issued after an HBM x prefetch inherits HBM latency at
// its use (consuming it forces vmcnt(0), draining the prefetch). Fix: the
// main loop's vm queue holds ONLY x loads; Wb is read from LDS (lgkm queue,
// independent). x A-fragments are 32 contiguous global bytes per lane ->
// loaded straight to registers, chunk-deep prefetch, ZERO main-loop barriers.
// Block = 512 thr (8 waves) = one batch-row PAIR per job; grid = 256 (1/CU,
// LDS 128 KiB caps it there anyway); each block loops over B/2/256 = 4 jobs,
// so the 96 KB Wb stage is amortized over the whole kernel.
// In flight: 8 waves x 8 KB = 64 KB/CU >> ~22 KB Little's-law need @6.3 TB/s.
// ---------------------------------------------------------------------------
__global__ __launch_bounds__(512, 2) void fused_kernel(
        const float* __restrict__ x,
        const uint4* __restrict__ Wb4,
        const float* __restrict__ Ssum,
        const float* __restrict__ bp,
        float* __restrict__ out,
        int nb2) {
    const int tid = threadIdx.x;
    const int w   = tid >> 6;   // wave 0..7
    const int l   = tid & 63;
    const int q   = l >> 4;     // quad 0..3 -> k-offset q*8 within 32-chunk
    const int n   = l & 15;     // A-row within wave's 16-row group
    const int wl  = w & 3;      // row-group within batch row
    const int bl  = w >> 2;     // which batch row of the pair

    // [0, 98304): Wb (identity copy of global layout); [98304, 131072): sout
    __shared__ __align__(16) char lds[98304 + 32768];

    // ---- stage Wb once (L2-hot after prep); only non-x vm traffic ----
    {
        uint4* wlds = (uint4*)lds;
        #pragma unroll
        for (int j = 0; j < 12; j++) {
            int idx = tid + j * 512;            // 6144 uint4 = 96 KB
            wlds[idx] = Wb4[idx];
        }
    }

    float St[4], Bt[4];
    #pragma unroll
    for (int t = 0; t < 4; t++) {
        St[t] = Ssum[t * 16 + n];   // o = 16t + n
        Bt[t] = bp[t * 16 + n];
    }
    __syncthreads();

    const int o2 = (n >> 2) & 3;
    const int o3 = n & 3;
    float* sout = (float*)(lds + 98304) + bl * 4096;

    for (int b2 = blockIdx.x; b2 < nb2; b2 += gridDim.x) {
        // lane's private x stream: batch row b2*2+bl, row wl*16+n, k base q*8
        const float* xr = x + (size_t)(b2 * 2 + bl) * 49152
                            + (wl * 16 + n) * 768 + q * 8;

        f32x4 acc0 = {0.f, 0.f, 0.f, 0.f};
        f32x4 acc1 = acc0, acc2 = acc0, acc3 = acc0;
        float sum = 0.f, ssq = 0.f;

        float4 cur[8], nxt[8];
        #pragma unroll
        for (int s = 0; s < 4; s++) {
            cur[2 * s]     = *(const float4*)(xr + s * 32);
            cur[2 * s + 1] = *(const float4*)(xr + s * 32 + 4);
        }

        #pragma unroll
        for (int c = 0; c < 6; c++) {
            // ---- issue next-chunk x loads first: full-chunk latency cover ----
            if (c < 5) {
                #pragma unroll
                for (int s = 0; s < 4; s++) {
                    nxt[2 * s]     = *(const float4*)(xr + (c + 1) * 128 + s * 32);
                    nxt[2 * s + 1] = *(const float4*)(xr + (c + 1) * 128 + s * 32 + 4);
                }
            }

            // ---- stats (fp32) + pack A-fragments to bf16 ----
            s16x8 af[4];
            #pragma unroll
            for (int s = 0; s < 4; s++) {
                float4 lo = cur[2 * s], hi = cur[2 * s + 1];
                sum += lo.x; ssq = fmaf(lo.x, lo.x, ssq);
                sum += lo.y; ssq = fmaf(lo.y, lo.y, ssq);
                sum += lo.z; ssq = fmaf(lo.z, lo.z, ssq);
                sum += lo.w; ssq = fmaf(lo.w, lo.w, ssq);
                sum += hi.x; ssq = fmaf(hi.x, hi.x, ssq);
                sum += hi.y; ssq = fmaf(hi.y, hi.y, ssq);
                sum += hi.z; ssq = fmaf(hi.z, hi.z, ssq);
                sum += hi.w; ssq = fmaf(hi.w, hi.w, ssq);
                CV2 p0, p1, p2, p3;
                p0.h = __float22bfloat162_rn(make_float2(lo.x, lo.y));
                p1.h = __float22bfloat162_rn(make_float2(lo.z, lo.w));
                p2.h = __float22bfloat162_rn(make_float2(hi.x, hi.y));
                p3.h = __float22bfloat162_rn(make_float2(hi.z, hi.w));
                af[s] = __builtin_bit_cast(s16x8,
                            make_uint4(p0.u, p1.u, p2.u, p3.u));
            }

            // ---- MFMA; B-fragments from LDS (lgkm queue, no vm dependency) ----
            const char* wbp = lds + c * 16384 + l * 16;
            #pragma unroll
            for (int s = 0; s < 4; s++) {
                uint4 wb0 = *(const uint4*)(wbp + (s * 4 + 0) * 1024);
                uint4 wb1 = *(const uint4*)(wbp + (s * 4 + 1) * 1024);
                uint4 wb2 = *(const uint4*)(wbp + (s * 4 + 2) * 1024);
                uint4 wb3 = *(const uint4*)(wbp + (s * 4 + 3) * 1024);
                acc0 = __builtin_amdgcn_mfma_f32_16x16x32_bf16(
                           af[s], __builtin_bit_cast(s16x8, wb0), acc0, 0, 0, 0);
                acc1 = __builtin_amdgcn_mfma_f32_16x16x32_bf16(
                           af[s], __builtin_bit_cast(s16x8, wb1), acc1, 0, 0, 0);
                acc2 = __builtin_amdgcn_mfma_f32_16x16x32_bf16(
                           af[s], __builtin_bit_cast(s16x8, wb2), acc2, 0, 0, 0);
                acc3 = __builtin_amdgcn_mfma_f32_16x16x32_bf16(
                           af[s], __builtin_bit_cast(s16x8, wb3), acc3, 0, 0, 0);
            }

            if (c < 5) {
                #pragma unroll
                for (int i = 0; i < 8; i++) cur[i] = nxt[i];
            }
        }

        // ---- row stats: reduce across the 4 lanes sharing row n ----
        sum += __shfl_xor(sum, 16); sum += __shfl_xor(sum, 32);
        ssq += __shfl_xor(ssq, 16); ssq += __shfl_xor(ssq, 32);
        const float mu   = sum * (1.0f / 768.0f);
        const float rstd = rsqrtf(ssq * (1.0f / 768.0f) - mu * mu + 1e-5f);

        // ---- epilogue: SiLU + unpatchify via LDS stage, coalesced stores ----
        f32x4 va[4] = {acc0, acc1, acc2, acc3};
        #pragma unroll
        for (int r = 0; r < 4; r++) {
            // D layout: lane holds row m = q*4+r, col n; stats live on lane m.
            float mu_r   = __shfl(mu,   q * 4 + r);
            float rstd_r = __shfl(rstd, q * 4 + r);
            int cc  = wl * 16 + q * 4 + r;
            int c1i = cc >> 3, c2i = cc & 7;
            int base = (c1i * 4 + o2) * 32 + c2i * 4 + o3;
            #pragma unroll
            for (int t = 0; t < 4; t++) {
                float y = rstd_r * (va[t][r] - mu_r * St[t]) + Bt[t];
                y = y / (1.0f + __expf(-y));             // SiLU
                sout[t * 1024 + base] = y;               // [c][c1*4+o2][c2*4+o3]
            }
        }
        __syncthreads();

        float* outp = out + (size_t)b2 * 8192;
        const float* sfl = (const float*)(lds + 98304);
        #pragma unroll
        for (int j = 0; j < 4; j++) {
            *(float4*)(outp + (j * 512 + tid) * 4) =
                *(const float4*)(sfl + (j * 512 + tid) * 4);
        }
        __syncthreads();   // sout readers done before next job overwrites
    }
}

extern "C" void kernel_launch(void* const* d_in, const int* in_sizes, int n_in,
                              void* d_out, int out_size, void* d_ws, size_t ws_size,
                              hipStream_t stream) {
    const float* x    = (const float*)d_in[0];
    const float* lnw  = (const float*)d_in[1];
    const float* lnb  = (const float*)d_in[2];
    const float* W    = (const float*)d_in[3];
    const float* bias = (const float*)d_in[4];
    float* out = (float*)d_out;

    const int B = in_sizes[0] / (64 * 768);   // 2048

    __hip_bfloat16* Wb = (__hip_bfloat16*)d_ws;                 // 98304 B
    float* Ssum = (float*)((char*)d_ws + 98304);                // 256 B
    float* bp   = (float*)((char*)d_ws + 98304 + 256);          // 256 B

    prep_kernel<<<64, 256, 0, stream>>>(W, lnw, lnb, bias, Wb, Ssum, bp);

    const int nb2  = B / 2;                   // batch-row pairs
    const int grid = nb2 < 256 ? nb2 : 256;
    fused_kernel<<<grid, 512, 0, stream>>>(x, (const uint4*)d_ws,
                                           Ssum, bp, out, nb2);
}